// Round 1
// baseline (936.880 us; speedup 1.0000x reference)
//
#include <hip/hip_runtime.h>
#include <hip/hip_bf16.h>
#include <stdint.h>

// Problem constants
#define S 1024
#define DMODEL 768
#define NH 12
#define DK 64
#define BB 4
#define BH 48      // BB*NH
#define M4 4096    // BB*S
#define NEGV -1e9f

typedef __attribute__((ext_vector_type(8))) short bf16x8;
typedef __attribute__((ext_vector_type(4))) float f32x4;

static __device__ __forceinline__ unsigned short f2bf(float f) {
  unsigned int u = __float_as_uint(f);
  unsigned int r = u + 0x7FFFu + ((u >> 16) & 1u);   // RNE
  return (unsigned short)(r >> 16);
}
static __device__ __forceinline__ float bf2f(unsigned short h) {
  return __uint_as_float(((unsigned int)h) << 16);
}
static __device__ __forceinline__ bf16x8 ldfrag(const unsigned short* p) {
  uint4 q = *reinterpret_cast<const uint4*>(p);
  return __builtin_bit_cast(bf16x8, q);
}

// ---------------- f32 -> bf16 elementwise convert ----------------
__global__ __launch_bounds__(256) void k_convert(const float* __restrict__ in,
                                                 unsigned short* __restrict__ out, int n4) {
  int i = blockIdx.x * 256 + threadIdx.x;
  if (i < n4) {
    float4 v = reinterpret_cast<const float4*>(in)[i];
    ushort4 o;
    o.x = f2bf(v.x); o.y = f2bf(v.y); o.z = f2bf(v.z); o.w = f2bf(v.w);
    reinterpret_cast<ushort4*>(out)[i] = o;
  }
}

// ---------------- W [k][n] f32 -> Wt [n][k] bf16 (768x768) ----------------
__global__ __launch_bounds__(256) void k_transpose(const float* w0, const float* w1, const float* w2,
                                                   unsigned short* o0, unsigned short* o1, unsigned short* o2) {
  const float* in = blockIdx.z == 0 ? w0 : (blockIdx.z == 1 ? w1 : w2);
  unsigned short* out = blockIdx.z == 0 ? o0 : (blockIdx.z == 1 ? o1 : o2);
  __shared__ float tile[32][33];
  int n0 = blockIdx.x * 32, k0 = blockIdx.y * 32;
  int tid = threadIdx.x;
  int r = tid >> 3, c = (tid & 7) * 4;
  float4 v = *reinterpret_cast<const float4*>(in + (size_t)(k0 + r) * DMODEL + n0 + c);
  tile[r][c] = v.x; tile[r][c + 1] = v.y; tile[r][c + 2] = v.z; tile[r][c + 3] = v.w;
  __syncthreads();
  ushort4 o;
  o.x = f2bf(tile[c + 0][r]);
  o.y = f2bf(tile[c + 1][r]);
  o.z = f2bf(tile[c + 2][r]);
  o.w = f2bf(tile[c + 3][r]);
  *reinterpret_cast<ushort4*>(out + (size_t)(n0 + r) * DMODEL + k0 + c) = o;
}

// ---------------- mask [BH][t][s] int32 -> bit arrays, both orientations ----------------
// mp1: bit(t) of word [bh][s][t>>5]  (mask for scores[s,t] path1)
// mp2: bit(s) of word [bh][t][s>>5]  (mask for scoresT[t,s] path2)
__global__ __launch_bounds__(256) void k_pack(const int* __restrict__ mask,
                                              unsigned int* __restrict__ mp1,
                                              unsigned int* __restrict__ mp2) {
  int bh = blockIdx.y;
  int t0 = blockIdx.x * 64;
  int w = threadIdx.x >> 6, lane = threadIdx.x & 63;
  const int* mb = mask + (size_t)bh * S * S;
  unsigned long long* p1 = reinterpret_cast<unsigned long long*>(mp1) + (size_t)bh * S * 16;
  unsigned long long* p2 = reinterpret_cast<unsigned long long*>(mp2) + (size_t)bh * S * 16;
  for (int s0 = 0; s0 < S; s0 += 64) {
    // direct orientation: rows t, bits along s (coalesced reads; warms L1)
    for (int r = w; r < 64; r += 4) {
      int v = mb[(size_t)(t0 + r) * S + s0 + lane];
      unsigned long long bits = __ballot(v != 0);
      if (lane == 0) p2[(size_t)(t0 + r) * 16 + (s0 >> 6)] = bits;
    }
    // transposed orientation: rows s, bits along t (gathers hit L1 from above)
    for (int sl = w; sl < 64; sl += 4) {
      int v = mb[(size_t)(t0 + lane) * S + s0 + sl];
      unsigned long long bits = __ballot(v != 0);
      if (lane == 0) p1[(size_t)(s0 + sl) * 16 + (t0 >> 6)] = bits;
    }
  }
}

// ---------------- 64x64-tile bf16 GEMM: C[4096x768] = A[4096x768] * Bt^T ----------------
// Bt is [n][k] row-major bf16. mode 0: write Q/K layout [BH][S][DK] bf16.
// mode 1: write f32 [4096][768] (pre-LayerNorm).
__global__ __launch_bounds__(256) void k_gemm64(
    int mode,
    const unsigned short* __restrict__ A0, const unsigned short* __restrict__ A1,
    const unsigned short* __restrict__ Bt0, const unsigned short* __restrict__ Bt1,
    unsigned short* __restrict__ oQ0, unsigned short* __restrict__ oQ1,
    float* __restrict__ oF0, float* __restrict__ oF1) {
  const unsigned short* A = blockIdx.z ? A1 : A0;
  const unsigned short* Bt = blockIdx.z ? Bt1 : Bt0;
  __shared__ __align__(16) unsigned short At[64 * 72];   // +8 pad: stride 144B (16B-aligned, 2-way banks)
  __shared__ __align__(16) unsigned short Btt[64 * 72];
  int tid = threadIdx.x;
  int m0 = blockIdx.x * 64, n0 = blockIdx.y * 64;
  int w = tid >> 6, lane = tid & 63, lane15 = lane & 15, quad = lane >> 4;
  int row0 = (w >> 1) * 32, col0 = (w & 1) * 32;   // wave computes 32x32
  f32x4 acc[2][2] = {};
  int sr = tid >> 2, sc = (tid & 3) * 16;
  for (int kc = 0; kc < 12; ++kc) {
    int k0 = kc * 64;
    const uint4* ga = reinterpret_cast<const uint4*>(A + (size_t)(m0 + sr) * DMODEL + k0 + sc);
    const uint4* gb = reinterpret_cast<const uint4*>(Bt + (size_t)(n0 + sr) * DMODEL + k0 + sc);
    uint4 a0v = ga[0], a1v = ga[1], b0v = gb[0], b1v = gb[1];
    __syncthreads();   // previous iter reads complete before overwrite
    *reinterpret_cast<uint4*>(&At[sr * 72 + sc]) = a0v;
    *reinterpret_cast<uint4*>(&At[sr * 72 + sc + 8]) = a1v;
    *reinterpret_cast<uint4*>(&Btt[sr * 72 + sc]) = b0v;
    *reinterpret_cast<uint4*>(&Btt[sr * 72 + sc + 8]) = b1v;
    __syncthreads();
#pragma unroll
    for (int ks = 0; ks < 2; ++ks) {
      int kk = ks * 32 + quad * 8;
      bf16x8 a0 = ldfrag(&At[(row0 + lane15) * 72 + kk]);
      bf16x8 a1 = ldfrag(&At[(row0 + 16 + lane15) * 72 + kk]);
      bf16x8 b0 = ldfrag(&Btt[(col0 + lane15) * 72 + kk]);
      bf16x8 b1 = ldfrag(&Btt[(col0 + 16 + lane15) * 72 + kk]);
      acc[0][0] = __builtin_amdgcn_mfma_f32_16x16x32_bf16(a0, b0, acc[0][0], 0, 0, 0);
      acc[0][1] = __builtin_amdgcn_mfma_f32_16x16x32_bf16(a0, b1, acc[0][1], 0, 0, 0);
      acc[1][0] = __builtin_amdgcn_mfma_f32_16x16x32_bf16(a1, b0, acc[1][0], 0, 0, 0);
      acc[1][1] = __builtin_amdgcn_mfma_f32_16x16x32_bf16(a1, b1, acc[1][1], 0, 0, 0);
    }
  }
  if (mode == 0) {
    unsigned short* out = blockIdx.z ? oQ1 : oQ0;
#pragma unroll
    for (int i = 0; i < 2; ++i)
#pragma unroll
      for (int j = 0; j < 2; ++j)
#pragma unroll
        for (int reg = 0; reg < 4; ++reg) {
          int m = m0 + row0 + i * 16 + quad * 4 + reg;   // C-layout: row=quad*4+reg, col=lane&15
          int n = n0 + col0 + j * 16 + lane15;
          int b = m >> 10, s = m & 1023, h = n >> 6, d = n & 63;
          out[(((size_t)(b * NH + h)) * S + s) * DK + d] = f2bf(acc[i][j][reg]);
        }
  } else {
    float* out = blockIdx.z ? oF1 : oF0;
#pragma unroll
    for (int i = 0; i < 2; ++i)
#pragma unroll
      for (int j = 0; j < 2; ++j)
#pragma unroll
        for (int reg = 0; reg < 4; ++reg) {
          int m = m0 + row0 + i * 16 + quad * 4 + reg;
          int n = n0 + col0 + j * 16 + lane15;
          out[(size_t)m * DMODEL + n] = acc[i][j][reg];
        }
  }
}

// ---------------- fused dual-path attention ----------------
// Per (bh, 16-row strip, path): out = rowsoftmax(mask(X Y^T / 8)) @ Y
// path0: X=Q, Y=K, mask=mp1, out=c1.  path1: X=K, Y=Q, mask=mp2, out=c2.
__global__ __launch_bounds__(256) void k_attn(
    const unsigned short* __restrict__ Qb, const unsigned short* __restrict__ Kb,
    const unsigned int* __restrict__ mp1, const unsigned int* __restrict__ mp2,
    unsigned short* __restrict__ c1, unsigned short* __restrict__ c2) {
  int bh = blockIdx.y;
  int s0 = blockIdx.x * 16;
  int path = blockIdx.z;
  const unsigned short* X = path ? Kb : Qb;
  const unsigned short* Y = path ? Qb : Kb;
  const unsigned int* mp = path ? mp2 : mp1;
  unsigned short* outc = path ? c2 : c1;

  __shared__ __align__(16) unsigned short XS[16 * 72];    // X strip, stride 72 (144B rows)
  __shared__ __align__(16) unsigned int MW[16 * 32];      // mask words for strip
  __shared__ __align__(16) unsigned short SS[16 * 1032];  // score strip bf16, stride 1032 (2064B rows)
  __shared__ __align__(16) unsigned short YS[64 * 72];    // Y tile (pass1: [j][d], pass2: [d][j])
  __shared__ float RI[16];                                // 1/rowsum

  const unsigned short* Xb = X + (size_t)bh * S * DK;
  const unsigned short* Yb = Y + (size_t)bh * S * DK;
  const unsigned int* mb = mp + ((size_t)bh * S + s0) * 32;

  int tid = threadIdx.x;
  int w = tid >> 6, lane = tid & 63, lane15 = lane & 15, quad = lane >> 4;

  // stage X strip (16x64 bf16) + mask words (16x32 u32)
  {
    int r = tid >> 4, d = (tid & 15) * 4;
    *reinterpret_cast<uint2*>(&XS[r * 72 + d]) =
        *reinterpret_cast<const uint2*>(Xb + (size_t)(s0 + r) * DK + d);
    reinterpret_cast<uint2*>(MW)[tid] = reinterpret_cast<const uint2*>(mb)[tid];
  }
  __syncthreads();

  int col0 = w * 16;
  // ---- Pass 1: scores strip = mask(X Y^T / 8) -> SS (bf16) ----
  for (int jt = 0; jt < 16; ++jt) {
    int j0 = jt * 64;
    {
      int r = tid >> 2, dd = (tid & 3) * 16;
      const uint4* g = reinterpret_cast<const uint4*>(Yb + (size_t)(j0 + r) * DK + dd);
      uint4 v0 = g[0], v1 = g[1];
      *reinterpret_cast<uint4*>(&YS[r * 72 + dd]) = v0;
      *reinterpret_cast<uint4*>(&YS[r * 72 + dd + 8]) = v1;
    }
    __syncthreads();
    f32x4 acc = {};
#pragma unroll
    for (int ks = 0; ks < 2; ++ks) {
      int kk = ks * 32 + quad * 8;
      bf16x8 a = ldfrag(&XS[lane15 * 72 + kk]);
      bf16x8 b = ldfrag(&YS[(col0 + lane15) * 72 + kk]);
      acc = __builtin_amdgcn_mfma_f32_16x16x32_bf16(a, b, acc, 0, 0, 0);
    }
    int t = j0 + col0 + lane15;
    unsigned int sh = t & 31;
#pragma unroll
    for (int reg = 0; reg < 4; ++reg) {
      int r = quad * 4 + reg;
      unsigned int wd = MW[r * 32 + (t >> 5)];
      float v = ((wd >> sh) & 1u) ? NEGV : acc[reg] * 0.125f;
      SS[r * 1032 + t] = f2bf(v);
    }
    __syncthreads();
  }

  // ---- softmax over each of 16 rows (1024 wide), in place, P stored bf16 ----
  {
    int row = tid >> 4, seg = tid & 15;
    unsigned short* base = &SS[row * 1032 + seg * 64];
    float mx = -3.0e38f;
#pragma unroll
    for (int c = 0; c < 8; ++c) {
      uint4 q = *reinterpret_cast<const uint4*>(base + c * 8);
      unsigned short* u = reinterpret_cast<unsigned short*>(&q);
#pragma unroll
      for (int i = 0; i < 8; ++i) mx = fmaxf(mx, bf2f(u[i]));
    }
#pragma unroll
    for (int m = 1; m < 16; m <<= 1) mx = fmaxf(mx, __shfl_xor(mx, m));
    float sum = 0.f;
#pragma unroll
    for (int c = 0; c < 8; ++c) {
      uint4 q = *reinterpret_cast<const uint4*>(base + c * 8);
      unsigned short* u = reinterpret_cast<unsigned short*>(&q);
      uint4 qo;
      unsigned short* uo = reinterpret_cast<unsigned short*>(&qo);
#pragma unroll
      for (int i = 0; i < 8; ++i) {
        float e = __expf(bf2f(u[i]) - mx);
        sum += e;
        uo[i] = f2bf(e);
      }
      *reinterpret_cast<uint4*>(base + c * 8) = qo;
    }
#pragma unroll
    for (int m = 1; m < 16; m <<= 1) sum += __shfl_xor(sum, m);
    if (seg == 0) RI[row] = 1.0f / sum;
  }
  __syncthreads();

  // ---- Pass 2: ctx = P @ Y (K=1024), Y staged transposed [d][j] ----
  f32x4 acc2 = {};
  int d0 = w * 16;
  for (int jt = 0; jt < 16; ++jt) {
    int j0 = jt * 64;
    {
      int r = tid >> 2, dd = (tid & 3) * 16;
      const uint4* g = reinterpret_cast<const uint4*>(Yb + (size_t)(j0 + r) * DK + dd);
      uint4 v0 = g[0], v1 = g[1];
      const unsigned short* u0 = reinterpret_cast<const unsigned short*>(&v0);
      const unsigned short* u1 = reinterpret_cast<const unsigned short*>(&v1);
      __syncthreads();   // prior iter's fragment reads complete
#pragma unroll
      for (int i = 0; i < 8; ++i) YS[(dd + i) * 72 + r] = u0[i];
#pragma unroll
      for (int i = 0; i < 8; ++i) YS[(dd + 8 + i) * 72 + r] = u1[i];
    }
    __syncthreads();
#pragma unroll
    for (int ks = 0; ks < 2; ++ks) {
      int kk = ks * 32 + quad * 8;
      bf16x8 a = ldfrag(&SS[lane15 * 1032 + j0 + kk]);
      bf16x8 b = ldfrag(&YS[(d0 + lane15) * 72 + kk]);
      acc2 = __builtin_amdgcn_mfma_f32_16x16x32_bf16(a, b, acc2, 0, 0, 0);
    }
  }

  int b = bh / NH, h = bh % NH;
#pragma unroll
  for (int reg = 0; reg < 4; ++reg) {
    int r = quad * 4 + reg;
    float v = acc2[reg] * RI[r];
    size_t idx = ((size_t)(b * S) + s0 + r) * DMODEL + h * DK + d0 + lane15;
    outc[idx] = f2bf(v);
  }
}

// ---------------- LayerNorm over 768, one block per row ----------------
__global__ __launch_bounds__(256) void k_ln(const float* __restrict__ f1, const float* __restrict__ f2,
                                            const float* __restrict__ g1, const float* __restrict__ b1,
                                            const float* __restrict__ g2, const float* __restrict__ b2,
                                            float* __restrict__ out) {
  int rowg = blockIdx.x;
  int sel = rowg >> 12;
  int row = rowg & 4095;
  const float* in = sel ? f2 : f1;
  const float* g = sel ? g2 : g1;
  const float* be = sel ? b2 : b1;
  int tid = threadIdx.x;
  const float* p = in + (size_t)row * DMODEL;
  float x0 = p[tid], x1 = p[tid + 256], x2 = p[tid + 512];
  float s = x0 + x1 + x2;
  float ss = x0 * x0 + x1 * x1 + x2 * x2;
#pragma unroll
  for (int m = 1; m < 64; m <<= 1) { s += __shfl_xor(s, m); ss += __shfl_xor(ss, m); }
  __shared__ float ps[4], pss[4];
  int w = tid >> 6;
  if ((tid & 63) == 0) { ps[w] = s; pss[w] = ss; }
  __syncthreads();
  s = ps[0] + ps[1] + ps[2] + ps[3];
  ss = pss[0] + pss[1] + pss[2] + pss[3];
  float mu = s * (1.0f / 768.0f);
  float var = ss * (1.0f / 768.0f) - mu * mu;
  float rstd = rsqrtf(var + 1e-5f);
  float* o = out + ((size_t)sel * M4 + row) * DMODEL;
  o[tid] = (x0 - mu) * rstd * g[tid] + be[tid];
  o[tid + 256] = (x1 - mu) * rstd * g[tid + 256] + be[tid + 256];
  o[tid + 512] = (x2 - mu) * rstd * g[tid + 512] + be[tid + 512];
}

extern "C" void kernel_launch(void* const* d_in, const int* in_sizes, int n_in,
                              void* d_out, int out_size, void* d_ws, size_t ws_size,
                              hipStream_t stream) {
  const float* pro1 = (const float*)d_in[0];
  const float* pro2 = (const float*)d_in[1];
  const int* mask = (const int*)d_in[2];
  const float* WQ = (const float*)d_in[3];
  const float* WK = (const float*)d_in[4];
  const float* FC1 = (const float*)d_in[5];
  const float* g1 = (const float*)d_in[6];
  const float* b1 = (const float*)d_in[7];
  const float* g2 = (const float*)d_in[8];
  const float* b2 = (const float*)d_in[9];
  float* out = (float*)d_out;
  char* ws = (char*)d_ws;

  // workspace layout (bytes); f1 overlays pro1b/pro2b, f2 overlays mp1/mp2 (lifetimes disjoint)
  unsigned short* pro1b = (unsigned short*)(ws + 0);          // 6291456
  unsigned short* pro2b = (unsigned short*)(ws + 6291456);    // 6291456
  float* f1 = (float*)(ws + 0);                               // 12582912 (after proj GEMM)
  unsigned short* wqt = (unsigned short*)(ws + 12582912);     // 1179648
  unsigned short* wkt = (unsigned short*)(ws + 13762560);     // 1179648
  unsigned short* fc1t = (unsigned short*)(ws + 14942208);    // 1179648
  unsigned short* Qb = (unsigned short*)(ws + 16121856);      // 6291456
  unsigned short* Kb = (unsigned short*)(ws + 22413312);      // 6291456
  unsigned int* mp1 = (unsigned int*)(ws + 28704768);         // 6291456
  unsigned int* mp2 = (unsigned int*)(ws + 34996224);         // 6291456
  float* f2 = (float*)(ws + 28704768);                        // 12582912 (after attn)
  unsigned short* c1 = (unsigned short*)(ws + 41287680);      // 6291456
  unsigned short* c2 = (unsigned short*)(ws + 47579136);      // 6291456
  // total: ~51.4 MB

  k_convert<<<3072, 256, 0, stream>>>(pro1, pro1b, 786432);
  k_convert<<<3072, 256, 0, stream>>>(pro2, pro2b, 786432);
  k_transpose<<<dim3(24, 24, 3), 256, 0, stream>>>(WQ, WK, FC1, wqt, wkt, fc1t);
  k_pack<<<dim3(16, BH), 256, 0, stream>>>(mask, mp1, mp2);
  k_gemm64<<<dim3(64, 12, 2), 256, 0, stream>>>(0, pro1b, pro2b, wqt, wkt, Qb, Kb, nullptr, nullptr);
  k_attn<<<dim3(64, BH, 2), 256, 0, stream>>>(Qb, Kb, mp1, mp2, c1, c2);
  k_gemm64<<<dim3(64, 12, 2), 256, 0, stream>>>(1, c1, c2, fc1t, fc1t, nullptr, nullptr, f1, f2);
  k_ln<<<8192, 256, 0, stream>>>(f1, f2, g1, b1, g2, b2, out);
}

// Round 2
// 565.976 us; speedup vs baseline: 1.6553x; 1.6553x over previous
//
#include <hip/hip_runtime.h>
#include <hip/hip_bf16.h>
#include <stdint.h>

// Problem constants
#define S 1024
#define DMODEL 768
#define NH 12
#define DK 64
#define BB 4
#define BH 48      // BB*NH
#define M4 4096    // BB*S
#define NEGV -1e9f

typedef __attribute__((ext_vector_type(8))) short bf16x8;
typedef __attribute__((ext_vector_type(4))) float f32x4;

static __device__ __forceinline__ unsigned short f2bf(float f) {
  unsigned int u = __float_as_uint(f);
  unsigned int r = u + 0x7FFFu + ((u >> 16) & 1u);   // RNE
  return (unsigned short)(r >> 16);
}
static __device__ __forceinline__ float bf2f(unsigned short h) {
  return __uint_as_float(((unsigned int)h) << 16);
}
static __device__ __forceinline__ bf16x8 ldfrag(const unsigned short* p) {
  uint4 q = *reinterpret_cast<const uint4*>(p);
  return __builtin_bit_cast(bf16x8, q);
}

// ---------------- f32 -> bf16 elementwise convert ----------------
__global__ __launch_bounds__(256) void k_convert(const float* __restrict__ in,
                                                 unsigned short* __restrict__ out, int n4) {
  int i = blockIdx.x * 256 + threadIdx.x;
  if (i < n4) {
    float4 v = reinterpret_cast<const float4*>(in)[i];
    ushort4 o;
    o.x = f2bf(v.x); o.y = f2bf(v.y); o.z = f2bf(v.z); o.w = f2bf(v.w);
    reinterpret_cast<ushort4*>(out)[i] = o;
  }
}

// ---------------- W [k][n] f32 -> Wt [n][k] bf16 (768x768) ----------------
__global__ __launch_bounds__(256) void k_transpose(const float* w0, const float* w1, const float* w2,
                                                   unsigned short* o0, unsigned short* o1, unsigned short* o2) {
  const float* in = blockIdx.z == 0 ? w0 : (blockIdx.z == 1 ? w1 : w2);
  unsigned short* out = blockIdx.z == 0 ? o0 : (blockIdx.z == 1 ? o1 : o2);
  __shared__ float tile[32][33];
  int n0 = blockIdx.x * 32, k0 = blockIdx.y * 32;
  int tid = threadIdx.x;
  int r = tid >> 3, c = (tid & 7) * 4;
  float4 v = *reinterpret_cast<const float4*>(in + (size_t)(k0 + r) * DMODEL + n0 + c);
  tile[r][c] = v.x; tile[r][c + 1] = v.y; tile[r][c + 2] = v.z; tile[r][c + 3] = v.w;
  __syncthreads();
  ushort4 o;
  o.x = f2bf(tile[c + 0][r]);
  o.y = f2bf(tile[c + 1][r]);
  o.z = f2bf(tile[c + 2][r]);
  o.w = f2bf(tile[c + 3][r]);
  *reinterpret_cast<ushort4*>(out + (size_t)(n0 + r) * DMODEL + k0 + c) = o;
}

// ---------------- mask [BH][t][s] int32 -> bit arrays (word-major), both orientations ----------------
// mp1[bh][wd=t>>5][s] bit(t&31) = mask[t][s]   (path0: rows s, cols t)
// mp2[bh][wd=s>>5][t] bit(s&31) = mask[t][s]   (path1: rows t, cols s)
// One wave per 64x64 tile: coalesced reads + ballot; transposed orientation via
// in-register 64x64 bit transpose (64 ballots), contiguous word-major writes.
__global__ __launch_bounds__(256) void k_pack(const int* __restrict__ mask,
                                              unsigned int* __restrict__ mp1,
                                              unsigned int* __restrict__ mp2) {
  int bh = blockIdx.y;
  int w = threadIdx.x >> 6, lane = threadIdx.x & 63;
  int tile = blockIdx.x * 4 + w;          // 0..255
  int ti = tile >> 4, tj = tile & 15;
  int t0 = ti * 64, s0 = tj * 64;
  const int* mb = mask + (size_t)bh * S * S;
  unsigned long long rowword = 0;
#pragma unroll 8
  for (int r = 0; r < 64; ++r) {
    int v = mb[(size_t)(t0 + r) * S + s0 + lane];
    unsigned long long b = __ballot(v != 0);
    if (lane == r) rowword = b;           // lane r holds bits over s for row t0+r
  }
  unsigned int* p2 = mp2 + (size_t)bh * 32 * S;
  p2[((s0 >> 5) + 0) * S + t0 + lane] = (unsigned int)rowword;
  p2[((s0 >> 5) + 1) * S + t0 + lane] = (unsigned int)(rowword >> 32);
  // bit-transpose: column word over t
  unsigned long long colword = 0;
#pragma unroll
  for (int s = 0; s < 64; ++s) {
    unsigned long long b = __ballot((rowword >> s) & 1ull);
    if (lane == s) colword = b;           // lane s holds bits over t for col s0+s
  }
  unsigned int* p1 = mp1 + (size_t)bh * 32 * S;
  p1[((t0 >> 5) + 0) * S + s0 + lane] = (unsigned int)colword;
  p1[((t0 >> 5) + 1) * S + s0 + lane] = (unsigned int)(colword >> 32);
}

// ---------------- 64x64-tile bf16 GEMM: C[4096x768] = A[4096x768] * Bt^T ----------------
// mode 0: write Q/K layout [BH][S][DK] bf16 AND transposed [BH][DK][S] bf16.
// mode 1: write f32 [4096][768] (pre-LayerNorm).
__global__ __launch_bounds__(256) void k_gemm64(
    int mode,
    const unsigned short* __restrict__ A0, const unsigned short* __restrict__ A1,
    const unsigned short* __restrict__ Bt0, const unsigned short* __restrict__ Bt1,
    unsigned short* __restrict__ oQ0, unsigned short* __restrict__ oQ1,
    unsigned short* __restrict__ oT0, unsigned short* __restrict__ oT1,
    float* __restrict__ oF0, float* __restrict__ oF1) {
  const unsigned short* A = blockIdx.z ? A1 : A0;
  const unsigned short* Bt = blockIdx.z ? Bt1 : Bt0;
  __shared__ __align__(16) unsigned short At[64 * 72];
  __shared__ __align__(16) unsigned short Btt[64 * 72];
  int tid = threadIdx.x;
  int m0 = blockIdx.x * 64, n0 = blockIdx.y * 64;
  int w = tid >> 6, lane = tid & 63, lane15 = lane & 15, quad = lane >> 4;
  int row0 = (w >> 1) * 32, col0 = (w & 1) * 32;
  f32x4 acc[2][2] = {};
  int sr = tid >> 2, sc = (tid & 3) * 16;
  for (int kc = 0; kc < 12; ++kc) {
    int k0 = kc * 64;
    const uint4* ga = reinterpret_cast<const uint4*>(A + (size_t)(m0 + sr) * DMODEL + k0 + sc);
    const uint4* gb = reinterpret_cast<const uint4*>(Bt + (size_t)(n0 + sr) * DMODEL + k0 + sc);
    uint4 a0v = ga[0], a1v = ga[1], b0v = gb[0], b1v = gb[1];
    __syncthreads();
    *reinterpret_cast<uint4*>(&At[sr * 72 + sc]) = a0v;
    *reinterpret_cast<uint4*>(&At[sr * 72 + sc + 8]) = a1v;
    *reinterpret_cast<uint4*>(&Btt[sr * 72 + sc]) = b0v;
    *reinterpret_cast<uint4*>(&Btt[sr * 72 + sc + 8]) = b1v;
    __syncthreads();
#pragma unroll
    for (int ks = 0; ks < 2; ++ks) {
      int kk = ks * 32 + quad * 8;
      bf16x8 a0 = ldfrag(&At[(row0 + lane15) * 72 + kk]);
      bf16x8 a1 = ldfrag(&At[(row0 + 16 + lane15) * 72 + kk]);
      bf16x8 b0 = ldfrag(&Btt[(col0 + lane15) * 72 + kk]);
      bf16x8 b1 = ldfrag(&Btt[(col0 + 16 + lane15) * 72 + kk]);
      acc[0][0] = __builtin_amdgcn_mfma_f32_16x16x32_bf16(a0, b0, acc[0][0], 0, 0, 0);
      acc[0][1] = __builtin_amdgcn_mfma_f32_16x16x32_bf16(a0, b1, acc[0][1], 0, 0, 0);
      acc[1][0] = __builtin_amdgcn_mfma_f32_16x16x32_bf16(a1, b0, acc[1][0], 0, 0, 0);
      acc[1][1] = __builtin_amdgcn_mfma_f32_16x16x32_bf16(a1, b1, acc[1][1], 0, 0, 0);
    }
  }
  if (mode == 0) {
    unsigned short* out = blockIdx.z ? oQ1 : oQ0;
    unsigned short* outT = blockIdx.z ? oT1 : oT0;
#pragma unroll
    for (int i = 0; i < 2; ++i)
#pragma unroll
      for (int j = 0; j < 2; ++j)
#pragma unroll
        for (int reg = 0; reg < 4; ++reg) {
          int m = m0 + row0 + i * 16 + quad * 4 + reg;
          int n = n0 + col0 + j * 16 + lane15;
          int b = m >> 10, s = m & 1023, h = n >> 6, d = n & 63;
          unsigned short bv = f2bf(acc[i][j][reg]);
          out[(((size_t)(b * NH + h)) * S + s) * DK + d] = bv;
          outT[(((size_t)(b * NH + h)) * DK + d) * S + s] = bv;
        }
  } else {
    float* out = blockIdx.z ? oF1 : oF0;
#pragma unroll
    for (int i = 0; i < 2; ++i)
#pragma unroll
      for (int j = 0; j < 2; ++j)
#pragma unroll
        for (int reg = 0; reg < 4; ++reg) {
          int m = m0 + row0 + i * 16 + quad * 4 + reg;
          int n = n0 + col0 + j * 16 + lane15;
          out[(size_t)m * DMODEL + n] = acc[i][j][reg];
        }
  }
}

// ---------------- fused dual-path attention (register-resident scores) ----------------
// Block = 16-row strip of one (bh, path). Wave w owns cols [w*256, w*256+256).
// pass1: scores in regs (C-layout). softmax: intra-quad shfl + cross-wave LDS.
// P -> LDS (A-layout, stride 264). pass2: B-frags from pre-transposed YT (global).
__global__ __launch_bounds__(256) void k_attn(
    const unsigned short* __restrict__ Qb, const unsigned short* __restrict__ Kb,
    const unsigned short* __restrict__ QT, const unsigned short* __restrict__ KT,
    const unsigned int* __restrict__ mp1, const unsigned int* __restrict__ mp2,
    unsigned short* __restrict__ c1, unsigned short* __restrict__ c2) {
  int strip = blockIdx.x, bh = blockIdx.y, path = blockIdx.z;
  int s0 = strip * 16;
  const unsigned short* X = path ? Kb : Qb;
  const unsigned short* Y = path ? Qb : Kb;
  const unsigned short* YT = path ? QT : KT;
  const unsigned int* mp = path ? mp2 : mp1;
  unsigned short* outc = path ? c2 : c1;

  __shared__ __align__(16) unsigned char SMEM[4 * 16 * 264 * 2];  // 33792 B: PS, later RED overlay
  __shared__ unsigned int MW[16 * 33];                            // mask words, stride 33 (bank-spread)
  __shared__ float SMX[64], SSUM[64], RI[16];
  unsigned short* PS = reinterpret_cast<unsigned short*>(SMEM);
  float* RED = reinterpret_cast<float*>(SMEM);

  const unsigned short* Xb = X + (size_t)bh * S * DK;
  const unsigned short* Yb = Y + (size_t)bh * S * DK;
  const unsigned short* YTb = YT + (size_t)bh * DK * S;
  const unsigned int* mb = mp + (size_t)bh * 32 * S;

  int tid = threadIdx.x;
  int w = tid >> 6, lane = tid & 63, lane15 = lane & 15, quad = lane >> 4;
  int jbase = w * 256;

  // stage mask words: MW[r][wd] = mb[wd*1024 + s0 + r]
  {
    int wd = tid >> 3, rp = (tid & 7) * 2;
    uint2 v = *reinterpret_cast<const uint2*>(mb + (size_t)wd * S + s0 + rp);
    MW[rp * 33 + wd] = v.x;
    MW[(rp + 1) * 33 + wd] = v.y;
  }

  // ---- pass1: scores strip (16 x 256 per wave) in registers ----
  bf16x8 af0 = ldfrag(Xb + (size_t)(s0 + lane15) * DK + quad * 8);
  bf16x8 af1 = ldfrag(Xb + (size_t)(s0 + lane15) * DK + 32 + quad * 8);
  f32x4 scq[16];
#pragma unroll
  for (int jt = 0; jt < 16; ++jt) {
    int j0 = jbase + jt * 16;
    bf16x8 b0 = ldfrag(Yb + (size_t)(j0 + lane15) * DK + quad * 8);
    bf16x8 b1 = ldfrag(Yb + (size_t)(j0 + lane15) * DK + 32 + quad * 8);
    f32x4 a = {};
    a = __builtin_amdgcn_mfma_f32_16x16x32_bf16(af0, b0, a, 0, 0, 0);
    a = __builtin_amdgcn_mfma_f32_16x16x32_bf16(af1, b1, a, 0, 0, 0);
    scq[jt] = a;
  }
  __syncthreads();   // MW visible

  // ---- mask + scale + row max (per quad, then cross-wave) ----
  float gmx[4];
#pragma unroll
  for (int reg = 0; reg < 4; ++reg) {
    int r = quad * 4 + reg;
    float mx = -3.0e38f;
#pragma unroll
    for (int jt = 0; jt < 16; ++jt) {
      int j0 = jbase + jt * 16;
      unsigned int wdv = MW[r * 33 + (j0 >> 5)];
      unsigned int sh = (unsigned)((j0 & 16) + lane15);
      float v = ((wdv >> sh) & 1u) ? NEGV : scq[jt][reg] * 0.125f;
      scq[jt][reg] = v;
      mx = fmaxf(mx, v);
    }
#pragma unroll
    for (int m = 1; m < 16; m <<= 1) mx = fmaxf(mx, __shfl_xor(mx, m));
    if (lane15 == 0) SMX[r * 4 + w] = mx;
    gmx[reg] = mx;
  }
  __syncthreads();
#pragma unroll
  for (int reg = 0; reg < 4; ++reg) {
    int r = quad * 4 + reg;
    gmx[reg] = fmaxf(fmaxf(SMX[r * 4 + 0], SMX[r * 4 + 1]),
                     fmaxf(SMX[r * 4 + 2], SMX[r * 4 + 3]));
  }

  // ---- exp, partial sums, write P (bf16, A-layout, stride 264) ----
  unsigned short* PSw = PS + w * (16 * 264);
#pragma unroll
  for (int reg = 0; reg < 4; ++reg) {
    int r = quad * 4 + reg;
    float sum = 0.f;
#pragma unroll
    for (int jt = 0; jt < 16; ++jt) {
      float e = __expf(scq[jt][reg] - gmx[reg]);
      sum += e;
      PSw[r * 264 + jt * 16 + lane15] = f2bf(e);
    }
#pragma unroll
    for (int m = 1; m < 16; m <<= 1) sum += __shfl_xor(sum, m);
    if (lane15 == 0) SSUM[r * 4 + w] = sum;
  }
  __syncthreads();
  if (tid < 16)
    RI[tid] = 1.0f / (SSUM[tid * 4 + 0] + SSUM[tid * 4 + 1] + SSUM[tid * 4 + 2] + SSUM[tid * 4 + 3]);

  // ---- pass2: ctx partial (16 x 64) over wave's j range; B-frags from YT global ----
  f32x4 ctx[4] = {};
#pragma unroll
  for (int kb = 0; kb < 8; ++kb) {
    int jl = kb * 32;
    bf16x8 pa = ldfrag(PSw + lane15 * 264 + jl + quad * 8);
    int jg = jbase + jl;
#pragma unroll
    for (int dt = 0; dt < 4; ++dt) {
      bf16x8 bb = ldfrag(YTb + (size_t)(dt * 16 + lane15) * S + jg + quad * 8);
      ctx[dt] = __builtin_amdgcn_mfma_f32_16x16x32_bf16(pa, bb, ctx[dt], 0, 0, 0);
    }
  }
  __syncthreads();   // all PS reads done -> RED overlay safe

  // ---- cross-wave reduction via LDS (stride 68: quads 2-way = free) ----
#pragma unroll
  for (int dt = 0; dt < 4; ++dt)
#pragma unroll
    for (int reg = 0; reg < 4; ++reg)
      RED[w * 1088 + (quad * 4 + reg) * 68 + dt * 16 + lane15] = ctx[dt][reg];
  __syncthreads();
  {
    int r = tid >> 4, ds = (tid & 15) * 4;
    float4 a0 = *reinterpret_cast<const float4*>(RED + 0 * 1088 + r * 68 + ds);
    float4 a1 = *reinterpret_cast<const float4*>(RED + 1 * 1088 + r * 68 + ds);
    float4 a2 = *reinterpret_cast<const float4*>(RED + 2 * 1088 + r * 68 + ds);
    float4 a3 = *reinterpret_cast<const float4*>(RED + 3 * 1088 + r * 68 + ds);
    float ri = RI[r];
    ushort4 o;
    o.x = f2bf((a0.x + a1.x + a2.x + a3.x) * ri);
    o.y = f2bf((a0.y + a1.y + a2.y + a3.y) * ri);
    o.z = f2bf((a0.z + a1.z + a2.z + a3.z) * ri);
    o.w = f2bf((a0.w + a1.w + a2.w + a3.w) * ri);
    int b = bh / NH, h = bh % NH;
    *reinterpret_cast<ushort4*>(outc + ((size_t)(b * S + s0 + r)) * DMODEL + h * DK + ds) = o;
  }
}

// ---------------- LayerNorm over 768, one block per row ----------------
__global__ __launch_bounds__(256) void k_ln(const float* __restrict__ f1, const float* __restrict__ f2,
                                            const float* __restrict__ g1, const float* __restrict__ b1,
                                            const float* __restrict__ g2, const float* __restrict__ b2,
                                            float* __restrict__ out) {
  int rowg = blockIdx.x;
  int sel = rowg >> 12;
  int row = rowg & 4095;
  const float* in = sel ? f2 : f1;
  const float* g = sel ? g2 : g1;
  const float* be = sel ? b2 : b1;
  int tid = threadIdx.x;
  const float* p = in + (size_t)row * DMODEL;
  float x0 = p[tid], x1 = p[tid + 256], x2 = p[tid + 512];
  float s = x0 + x1 + x2;
  float ss = x0 * x0 + x1 * x1 + x2 * x2;
#pragma unroll
  for (int m = 1; m < 64; m <<= 1) { s += __shfl_xor(s, m); ss += __shfl_xor(ss, m); }
  __shared__ float ps[4], pss[4];
  int w = tid >> 6;
  if ((tid & 63) == 0) { ps[w] = s; pss[w] = ss; }
  __syncthreads();
  s = ps[0] + ps[1] + ps[2] + ps[3];
  ss = pss[0] + pss[1] + pss[2] + pss[3];
  float mu = s * (1.0f / 768.0f);
  float var = ss * (1.0f / 768.0f) - mu * mu;
  float rstd = rsqrtf(var + 1e-5f);
  float* o = out + ((size_t)sel * M4 + row) * DMODEL;
  o[tid] = (x0 - mu) * rstd * g[tid] + be[tid];
  o[tid + 256] = (x1 - mu) * rstd * g[tid + 256] + be[tid + 256];
  o[tid + 512] = (x2 - mu) * rstd * g[tid + 512] + be[tid + 512];
}

extern "C" void kernel_launch(void* const* d_in, const int* in_sizes, int n_in,
                              void* d_out, int out_size, void* d_ws, size_t ws_size,
                              hipStream_t stream) {
  const float* pro1 = (const float*)d_in[0];
  const float* pro2 = (const float*)d_in[1];
  const int* mask = (const int*)d_in[2];
  const float* WQ = (const float*)d_in[3];
  const float* WK = (const float*)d_in[4];
  const float* FC1 = (const float*)d_in[5];
  const float* g1 = (const float*)d_in[6];
  const float* b1 = (const float*)d_in[7];
  const float* g2 = (const float*)d_in[8];
  const float* b2 = (const float*)d_in[9];
  float* out = (float*)d_out;
  char* ws = (char*)d_ws;

  // workspace layout (bytes)
  unsigned short* pro1b = (unsigned short*)(ws + 0);          // 6291456
  unsigned short* pro2b = (unsigned short*)(ws + 6291456);    // 6291456
  float* f1 = (float*)(ws + 0);                               // overlays pro1b/pro2b (dead by then)
  unsigned short* wqt = (unsigned short*)(ws + 12582912);     // 1179648
  unsigned short* wkt = (unsigned short*)(ws + 13762560);     // 1179648
  unsigned short* fc1t = (unsigned short*)(ws + 14942208);    // 1179648
  unsigned short* Qb = (unsigned short*)(ws + 16121856);      // 6291456
  unsigned short* Kb = (unsigned short*)(ws + 22413312);      // 6291456
  unsigned short* QT = (unsigned short*)(ws + 28704768);      // 6291456
  unsigned short* KT = (unsigned short*)(ws + 34996224);      // 6291456
  unsigned int* mp1 = (unsigned int*)(ws + 41287680);         // 6291456
  unsigned int* mp2 = (unsigned int*)(ws + 47579136);         // 6291456
  float* f2 = (float*)(ws + 41287680);                        // overlays mp1/mp2 (dead after attn)
  unsigned short* c1 = (unsigned short*)(ws + 53870592);      // 6291456
  unsigned short* c2 = (unsigned short*)(ws + 60162048);      // 6291456
  // total ~66.5 MB

  k_convert<<<3072, 256, 0, stream>>>(pro1, pro1b, 786432);
  k_convert<<<3072, 256, 0, stream>>>(pro2, pro2b, 786432);
  k_transpose<<<dim3(24, 24, 3), 256, 0, stream>>>(WQ, WK, FC1, wqt, wkt, fc1t);
  k_pack<<<dim3(64, BH), 256, 0, stream>>>(mask, mp1, mp2);
  k_gemm64<<<dim3(64, 12, 2), 256, 0, stream>>>(0, pro1b, pro2b, wqt, wkt, Qb, Kb, QT, KT, nullptr, nullptr);
  k_attn<<<dim3(64, BH, 2), 256, 0, stream>>>(Qb, Kb, QT, KT, mp1, mp2, c1, c2);
  k_gemm64<<<dim3(64, 12, 2), 256, 0, stream>>>(1, c1, c2, fc1t, fc1t, nullptr, nullptr, nullptr, nullptr, f1, f2);
  k_ln<<<8192, 256, 0, stream>>>(f1, f2, g1, b1, g2, b2, out);
}

// Round 3
// 442.406 us; speedup vs baseline: 2.1177x; 1.2793x over previous
//
#include <hip/hip_runtime.h>
#include <hip/hip_bf16.h>
#include <stdint.h>

// Problem constants
#define S 1024
#define DMODEL 768
#define NH 12
#define DK 64
#define BB 4
#define BH 48      // BB*NH
#define M4 4096    // BB*S
#define NEGV -1e9f

typedef __attribute__((ext_vector_type(8))) short bf16x8;
typedef __attribute__((ext_vector_type(4))) float f32x4;

static __device__ __forceinline__ unsigned short f2bf(float f) {
  unsigned int u = __float_as_uint(f);
  unsigned int r = u + 0x7FFFu + ((u >> 16) & 1u);   // RNE
  return (unsigned short)(r >> 16);
}
static __device__ __forceinline__ float bf2f(unsigned short h) {
  return __uint_as_float(((unsigned int)h) << 16);
}
static __device__ __forceinline__ bf16x8 ldfrag(const unsigned short* p) {
  uint4 q = *reinterpret_cast<const uint4*>(p);
  return __builtin_bit_cast(bf16x8, q);
}

// ---------------- f32 -> bf16 elementwise convert ----------------
__global__ __launch_bounds__(256) void k_convert(const float* __restrict__ in,
                                                 unsigned short* __restrict__ out, int n4) {
  int i = blockIdx.x * 256 + threadIdx.x;
  if (i < n4) {
    float4 v = reinterpret_cast<const float4*>(in)[i];
    ushort4 o;
    o.x = f2bf(v.x); o.y = f2bf(v.y); o.z = f2bf(v.z); o.w = f2bf(v.w);
    reinterpret_cast<ushort4*>(out)[i] = o;
  }
}

// ---------------- W [k][n] f32 -> Wt [n][k] bf16 (768x768) ----------------
__global__ __launch_bounds__(256) void k_transpose(const float* w0, const float* w1, const float* w2,
                                                   unsigned short* o0, unsigned short* o1, unsigned short* o2) {
  const float* in = blockIdx.z == 0 ? w0 : (blockIdx.z == 1 ? w1 : w2);
  unsigned short* out = blockIdx.z == 0 ? o0 : (blockIdx.z == 1 ? o1 : o2);
  __shared__ float tile[32][33];
  int n0 = blockIdx.x * 32, k0 = blockIdx.y * 32;
  int tid = threadIdx.x;
  int r = tid >> 3, c = (tid & 7) * 4;
  float4 v = *reinterpret_cast<const float4*>(in + (size_t)(k0 + r) * DMODEL + n0 + c);
  tile[r][c] = v.x; tile[r][c + 1] = v.y; tile[r][c + 2] = v.z; tile[r][c + 3] = v.w;
  __syncthreads();
  ushort4 o;
  o.x = f2bf(tile[c + 0][r]);
  o.y = f2bf(tile[c + 1][r]);
  o.z = f2bf(tile[c + 2][r]);
  o.w = f2bf(tile[c + 3][r]);
  *reinterpret_cast<ushort4*>(out + (size_t)(n0 + r) * DMODEL + k0 + c) = o;
}

// ---------------- mask [BH][t][s] int32 -> bit arrays (word-major), both orientations ----------------
// mp1[bh][wd=t>>5][s] bit(t&31) = mask[t][s]   (path0: rows s, cols t)
// mp2[bh][wd=s>>5][t] bit(s&31) = mask[t][s]   (path1: rows t, cols s)
__global__ __launch_bounds__(256) void k_pack(const int* __restrict__ mask,
                                              unsigned int* __restrict__ mp1,
                                              unsigned int* __restrict__ mp2) {
  int bh = blockIdx.y;
  int w = threadIdx.x >> 6, lane = threadIdx.x & 63;
  int tile = blockIdx.x * 4 + w;          // 0..255
  int ti = tile >> 4, tj = tile & 15;
  int t0 = ti * 64, s0 = tj * 64;
  const int* mb = mask + (size_t)bh * S * S;
  unsigned long long rowword = 0;
#pragma unroll 8
  for (int r = 0; r < 64; ++r) {
    int v = mb[(size_t)(t0 + r) * S + s0 + lane];
    unsigned long long b = __ballot(v != 0);
    if (lane == r) rowword = b;           // lane r holds bits over s for row t0+r
  }
  unsigned int* p2 = mp2 + (size_t)bh * 32 * S;
  p2[((s0 >> 5) + 0) * S + t0 + lane] = (unsigned int)rowword;
  p2[((s0 >> 5) + 1) * S + t0 + lane] = (unsigned int)(rowword >> 32);
  // bit-transpose: column word over t
  unsigned long long colword = 0;
#pragma unroll
  for (int s = 0; s < 64; ++s) {
    unsigned long long b = __ballot((rowword >> s) & 1ull);
    if (lane == s) colword = b;           // lane s holds bits over t for col s0+s
  }
  unsigned int* p1 = mp1 + (size_t)bh * 32 * S;
  p1[((t0 >> 5) + 0) * S + s0 + lane] = (unsigned int)colword;
  p1[((t0 >> 5) + 1) * S + s0 + lane] = (unsigned int)(colword >> 32);
}

// ---------------- 128x128-tile bf16 GEMM: C[4096x768] = A[4096x768] * Bt^T ----------------
// Bt is [n][k] row-major bf16. mode 0: write Q/K [BH][S][DK] + transposed [BH][DK][S].
// mode 1: write f32 [4096][768] (pre-LayerNorm).
__global__ __launch_bounds__(256) void k_gemm128(
    int mode,
    const unsigned short* __restrict__ A0, const unsigned short* __restrict__ A1,
    const unsigned short* __restrict__ Bt0, const unsigned short* __restrict__ Bt1,
    unsigned short* __restrict__ oQ0, unsigned short* __restrict__ oQ1,
    unsigned short* __restrict__ oT0, unsigned short* __restrict__ oT1,
    float* __restrict__ oF0, float* __restrict__ oF1) {
  const unsigned short* A = blockIdx.z ? A1 : A0;
  const unsigned short* Bt = blockIdx.z ? Bt1 : Bt0;
  __shared__ __align__(16) unsigned short As[128 * 72];   // 18432 B
  __shared__ __align__(16) unsigned short Bs[128 * 72];   // 18432 B
  int tid = threadIdx.x;
  int m0 = blockIdx.x * 128, n0 = blockIdx.y * 128;
  int w = tid >> 6, lane = tid & 63, lane15 = lane & 15, quad = lane >> 4;
  int row0 = (w >> 1) * 64, col0 = (w & 1) * 64;
  f32x4 acc[4][4] = {};
  int sr = tid >> 2, sc = (tid & 3) * 16;
  const unsigned short* gA0 = A + (size_t)(m0 + sr) * DMODEL + sc;
  const unsigned short* gA1 = A + (size_t)(m0 + 64 + sr) * DMODEL + sc;
  const unsigned short* gB0 = Bt + (size_t)(n0 + sr) * DMODEL + sc;
  const unsigned short* gB1 = Bt + (size_t)(n0 + 64 + sr) * DMODEL + sc;
  uint4 va0 = *reinterpret_cast<const uint4*>(gA0);
  uint4 va1 = *reinterpret_cast<const uint4*>(gA1);
  uint4 vb0 = *reinterpret_cast<const uint4*>(gB0);
  uint4 vb1 = *reinterpret_cast<const uint4*>(gB1);
  uint4 va0b = *reinterpret_cast<const uint4*>(gA0 + 8);
  uint4 va1b = *reinterpret_cast<const uint4*>(gA1 + 8);
  uint4 vb0b = *reinterpret_cast<const uint4*>(gB0 + 8);
  uint4 vb1b = *reinterpret_cast<const uint4*>(gB1 + 8);
  for (int kc = 0; kc < 12; ++kc) {
    __syncthreads();   // prior iter frag reads complete
    *reinterpret_cast<uint4*>(&As[sr * 72 + sc]) = va0;
    *reinterpret_cast<uint4*>(&As[sr * 72 + sc + 8]) = va0b;
    *reinterpret_cast<uint4*>(&As[(64 + sr) * 72 + sc]) = va1;
    *reinterpret_cast<uint4*>(&As[(64 + sr) * 72 + sc + 8]) = va1b;
    *reinterpret_cast<uint4*>(&Bs[sr * 72 + sc]) = vb0;
    *reinterpret_cast<uint4*>(&Bs[sr * 72 + sc + 8]) = vb0b;
    *reinterpret_cast<uint4*>(&Bs[(64 + sr) * 72 + sc]) = vb1;
    *reinterpret_cast<uint4*>(&Bs[(64 + sr) * 72 + sc + 8]) = vb1b;
    if (kc < 11) {
      int k0 = (kc + 1) * 64;
      va0 = *reinterpret_cast<const uint4*>(gA0 + k0);
      va1 = *reinterpret_cast<const uint4*>(gA1 + k0);
      vb0 = *reinterpret_cast<const uint4*>(gB0 + k0);
      vb1 = *reinterpret_cast<const uint4*>(gB1 + k0);
      va0b = *reinterpret_cast<const uint4*>(gA0 + k0 + 8);
      va1b = *reinterpret_cast<const uint4*>(gA1 + k0 + 8);
      vb0b = *reinterpret_cast<const uint4*>(gB0 + k0 + 8);
      vb1b = *reinterpret_cast<const uint4*>(gB1 + k0 + 8);
    }
    __syncthreads();
#pragma unroll
    for (int ks = 0; ks < 2; ++ks) {
      int kk = ks * 32 + quad * 8;
      bf16x8 a[4], b[4];
#pragma unroll
      for (int i = 0; i < 4; ++i) a[i] = ldfrag(&As[(row0 + i * 16 + lane15) * 72 + kk]);
#pragma unroll
      for (int j = 0; j < 4; ++j) b[j] = ldfrag(&Bs[(col0 + j * 16 + lane15) * 72 + kk]);
#pragma unroll
      for (int i = 0; i < 4; ++i)
#pragma unroll
        for (int j = 0; j < 4; ++j)
          acc[i][j] = __builtin_amdgcn_mfma_f32_16x16x32_bf16(a[i], b[j], acc[i][j], 0, 0, 0);
    }
  }
  if (mode == 0) {
    unsigned short* out = blockIdx.z ? oQ1 : oQ0;
    unsigned short* outT = blockIdx.z ? oT1 : oT0;
#pragma unroll
    for (int i = 0; i < 4; ++i)
#pragma unroll
      for (int j = 0; j < 4; ++j)
#pragma unroll
        for (int reg = 0; reg < 4; ++reg) {
          int m = m0 + row0 + i * 16 + quad * 4 + reg;
          int n = n0 + col0 + j * 16 + lane15;
          int b = m >> 10, s = m & 1023, h = n >> 6, d = n & 63;
          unsigned short bv = f2bf(acc[i][j][reg]);
          out[(((size_t)(b * NH + h)) * S + s) * DK + d] = bv;
          outT[(((size_t)(b * NH + h)) * DK + d) * S + s] = bv;
        }
  } else {
    float* out = blockIdx.z ? oF1 : oF0;
#pragma unroll
    for (int i = 0; i < 4; ++i)
#pragma unroll
      for (int j = 0; j < 4; ++j)
#pragma unroll
        for (int reg = 0; reg < 4; ++reg) {
          int m = m0 + row0 + i * 16 + quad * 4 + reg;
          int n = n0 + col0 + j * 16 + lane15;
          out[(size_t)m * DMODEL + n] = acc[i][j][reg];
        }
  }
}

// ---------------- fused dual-path attention: single-pass, no-max softmax ----------------
// Block = (bh, path, 64 rows); wave w owns rows [s0b + w*16, +16).
// Stream 16 chunks of 64 j: Y+YT chunk staged in LDS (shared by 4 waves),
// scores->exp->P(LDS, wave-private)->PV, row-sum accumulated in regs. No second pass:
// exp without max-subtraction (scores O(10), masked lanes exact 0).
__global__ __launch_bounds__(256, 4) void k_attn(
    const unsigned short* __restrict__ Qb, const unsigned short* __restrict__ Kb,
    const unsigned short* __restrict__ QT, const unsigned short* __restrict__ KT,
    const unsigned int* __restrict__ mp1, const unsigned int* __restrict__ mp2,
    unsigned short* __restrict__ c1, unsigned short* __restrict__ c2) {
  int bh = blockIdx.y, path = blockIdx.z;
  int s0b = blockIdx.x * 64;
  const unsigned short* X = path ? Kb : Qb;
  const unsigned short* Y = path ? Qb : Kb;
  const unsigned short* YT = path ? QT : KT;
  const unsigned int* mp = path ? mp2 : mp1;
  unsigned short* outc = path ? c2 : c1;

  __shared__ __align__(16) unsigned short YS[64 * 72];    // Y chunk [j][d]
  __shared__ __align__(16) unsigned short YTS[64 * 72];   // YT chunk [d][j]
  __shared__ __align__(16) unsigned short PS[4][16 * 72]; // per-wave P
  __shared__ unsigned int MW[64 * 33];                    // mask words for 64 rows

  const unsigned short* Xb = X + (size_t)bh * S * DK;
  const unsigned short* Yb = Y + (size_t)bh * S * DK;
  const unsigned short* YTb = YT + (size_t)bh * DK * S;
  const unsigned int* mb = mp + (size_t)bh * 32 * S;

  int tid = threadIdx.x;
  int w = tid >> 6, lane = tid & 63, lane15 = lane & 15, quad = lane >> 4;
  int s0 = s0b + w * 16;

  // stage mask words for the block's 64 rows: MW[r][wd] = mb[wd*S + s0b + r]
  {
    int wd = tid >> 3, r8 = (tid & 7) * 8;
    uint4 v0 = *reinterpret_cast<const uint4*>(mb + (size_t)wd * S + s0b + r8);
    uint4 v1 = *reinterpret_cast<const uint4*>(mb + (size_t)wd * S + s0b + r8 + 4);
    MW[(r8 + 0) * 33 + wd] = v0.x; MW[(r8 + 1) * 33 + wd] = v0.y;
    MW[(r8 + 2) * 33 + wd] = v0.z; MW[(r8 + 3) * 33 + wd] = v0.w;
    MW[(r8 + 4) * 33 + wd] = v1.x; MW[(r8 + 5) * 33 + wd] = v1.y;
    MW[(r8 + 6) * 33 + wd] = v1.z; MW[(r8 + 7) * 33 + wd] = v1.w;
  }

  // X fragments (A-operand): rows s0..s0+16
  bf16x8 af0 = ldfrag(Xb + (size_t)(s0 + lane15) * DK + quad * 8);
  bf16x8 af1 = ldfrag(Xb + (size_t)(s0 + lane15) * DK + 32 + quad * 8);

  // staging addresses: thread covers row sr4 (0..63), 16 cols at sc4
  int sr4 = tid >> 2, sc4 = (tid & 3) * 16;
  const unsigned short* gY = Yb + (size_t)sr4 * DK + sc4;        // + j0*DK
  const unsigned short* gYT = YTb + (size_t)sr4 * S + sc4;       // + j0
  uint4 y0 = *reinterpret_cast<const uint4*>(gY);
  uint4 y1 = *reinterpret_cast<const uint4*>(gY + 8);
  uint4 t0 = *reinterpret_cast<const uint4*>(gYT);
  uint4 t1 = *reinterpret_cast<const uint4*>(gYT + 8);

  f32x4 outa[4] = {};
  float lsum[4] = {0.f, 0.f, 0.f, 0.f};
  unsigned short* PSw = PS[w];

  for (int jc = 0; jc < 16; ++jc) {
    __syncthreads();   // prior chunk frag reads complete
    *reinterpret_cast<uint4*>(&YS[sr4 * 72 + sc4]) = y0;
    *reinterpret_cast<uint4*>(&YS[sr4 * 72 + sc4 + 8]) = y1;
    *reinterpret_cast<uint4*>(&YTS[sr4 * 72 + sc4]) = t0;
    *reinterpret_cast<uint4*>(&YTS[sr4 * 72 + sc4 + 8]) = t1;
    {
      int jn = (jc + 1 < 16) ? (jc + 1) * 64 : jc * 64;   // clamped prefetch
      y0 = *reinterpret_cast<const uint4*>(gY + (size_t)jn * DK);
      y1 = *reinterpret_cast<const uint4*>(gY + (size_t)jn * DK + 8);
      t0 = *reinterpret_cast<const uint4*>(gYT + jn);
      t1 = *reinterpret_cast<const uint4*>(gYT + jn + 8);
    }
    __syncthreads();   // staging visible

    int j0 = jc * 64;
    // scores: 4 subtiles of 16 j, K=64
    f32x4 sc[4];
#pragma unroll
    for (int st = 0; st < 4; ++st) {
      bf16x8 b0 = ldfrag(&YS[(st * 16 + lane15) * 72 + quad * 8]);
      bf16x8 b1 = ldfrag(&YS[(st * 16 + lane15) * 72 + 32 + quad * 8]);
      f32x4 a = {};
      a = __builtin_amdgcn_mfma_f32_16x16x32_bf16(af0, b0, a, 0, 0, 0);
      a = __builtin_amdgcn_mfma_f32_16x16x32_bf16(af1, b1, a, 0, 0, 0);
      sc[st] = a;
    }
    // mask words: row = w*16 + quad*4 + reg, words j0>>5 and j0>>5 + 1 (broadcast reads)
    int w0 = j0 >> 5;
    unsigned int mw0[4], mw1[4];
#pragma unroll
    for (int reg = 0; reg < 4; ++reg) {
      int r = w * 16 + quad * 4 + reg;
      mw0[reg] = MW[r * 33 + w0];
      mw1[reg] = MW[r * 33 + w0 + 1];
    }
    // exp (no max), mask->0, accumulate row sums, store P
#pragma unroll
    for (int st = 0; st < 4; ++st) {
      unsigned int sh = (unsigned)((st & 1) * 16 + lane15);
#pragma unroll
      for (int reg = 0; reg < 4; ++reg) {
        unsigned int wd = (st < 2) ? mw0[reg] : mw1[reg];
        float e = __expf(sc[st][reg] * 0.125f);
        float p = ((wd >> sh) & 1u) ? 0.f : e;
        lsum[reg] += p;
        PSw[(quad * 4 + reg) * 72 + st * 16 + lane15] = f2bf(p);
      }
    }
    // PV: out += P @ Y  (K=64 in 2 halves; B from YTS)
#pragma unroll
    for (int half = 0; half < 2; ++half) {
      bf16x8 pa = ldfrag(&PSw[lane15 * 72 + half * 32 + quad * 8]);
#pragma unroll
      for (int dt = 0; dt < 4; ++dt) {
        bf16x8 bb = ldfrag(&YTS[(dt * 16 + lane15) * 72 + half * 32 + quad * 8]);
        outa[dt] = __builtin_amdgcn_mfma_f32_16x16x32_bf16(pa, bb, outa[dt], 0, 0, 0);
      }
    }
  }

  // reduce row sums across the 16 lanes of each quad-row group
#pragma unroll
  for (int reg = 0; reg < 4; ++reg) {
#pragma unroll
    for (int m = 1; m < 16; m <<= 1) lsum[reg] += __shfl_xor(lsum[reg], m);
    lsum[reg] = 1.0f / lsum[reg];
  }
  int b = bh / NH, h = bh % NH;
#pragma unroll
  for (int dt = 0; dt < 4; ++dt)
#pragma unroll
    for (int reg = 0; reg < 4; ++reg) {
      float v = outa[dt][reg] * lsum[reg];
      size_t idx = ((size_t)(b * S) + s0 + quad * 4 + reg) * DMODEL + h * DK + dt * 16 + lane15;
      outc[idx] = f2bf(v);
    }
}

// ---------------- LayerNorm over 768, one block per row ----------------
__global__ __launch_bounds__(256) void k_ln(const float* __restrict__ f1, const float* __restrict__ f2,
                                            const float* __restrict__ g1, const float* __restrict__ b1,
                                            const float* __restrict__ g2, const float* __restrict__ b2,
                                            float* __restrict__ out) {
  int rowg = blockIdx.x;
  int sel = rowg >> 12;
  int row = rowg & 4095;
  const float* in = sel ? f2 : f1;
  const float* g = sel ? g2 : g1;
  const float* be = sel ? b2 : b1;
  int tid = threadIdx.x;
  const float* p = in + (size_t)row * DMODEL;
  float x0 = p[tid], x1 = p[tid + 256], x2 = p[tid + 512];
  float s = x0 + x1 + x2;
  float ss = x0 * x0 + x1 * x1 + x2 * x2;
#pragma unroll
  for (int m = 1; m < 64; m <<= 1) { s += __shfl_xor(s, m); ss += __shfl_xor(ss, m); }
  __shared__ float ps[4], pss[4];
  int w = tid >> 6;
  if ((tid & 63) == 0) { ps[w] = s; pss[w] = ss; }
  __syncthreads();
  s = ps[0] + ps[1] + ps[2] + ps[3];
  ss = pss[0] + pss[1] + pss[2] + pss[3];
  float mu = s * (1.0f / 768.0f);
  float var = ss * (1.0f / 768.0f) - mu * mu;
  float rstd = rsqrtf(var + 1e-5f);
  float* o = out + ((size_t)sel * M4 + row) * DMODEL;
  o[tid] = (x0 - mu) * rstd * g[tid] + be[tid];
  o[tid + 256] = (x1 - mu) * rstd * g[tid + 256] + be[tid + 256];
  o[tid + 512] = (x2 - mu) * rstd * g[tid + 512] + be[tid + 512];
}

extern "C" void kernel_launch(void* const* d_in, const int* in_sizes, int n_in,
                              void* d_out, int out_size, void* d_ws, size_t ws_size,
                              hipStream_t stream) {
  const float* pro1 = (const float*)d_in[0];
  const float* pro2 = (const float*)d_in[1];
  const int* mask = (const int*)d_in[2];
  const float* WQ = (const float*)d_in[3];
  const float* WK = (const float*)d_in[4];
  const float* FC1 = (const float*)d_in[5];
  const float* g1 = (const float*)d_in[6];
  const float* b1 = (const float*)d_in[7];
  const float* g2 = (const float*)d_in[8];
  const float* b2 = (const float*)d_in[9];
  float* out = (float*)d_out;
  char* ws = (char*)d_ws;

  // workspace layout (bytes)
  unsigned short* pro1b = (unsigned short*)(ws + 0);          // 6291456
  unsigned short* pro2b = (unsigned short*)(ws + 6291456);    // 6291456
  float* f1 = (float*)(ws + 0);                               // overlays pro1b/pro2b (dead by then)
  unsigned short* wqt = (unsigned short*)(ws + 12582912);     // 1179648
  unsigned short* wkt = (unsigned short*)(ws + 13762560);     // 1179648
  unsigned short* fc1t = (unsigned short*)(ws + 14942208);    // 1179648
  unsigned short* Qb = (unsigned short*)(ws + 16121856);      // 6291456
  unsigned short* Kb = (unsigned short*)(ws + 22413312);      // 6291456
  unsigned short* QT = (unsigned short*)(ws + 28704768);      // 6291456
  unsigned short* KT = (unsigned short*)(ws + 34996224);      // 6291456
  unsigned int* mp1 = (unsigned int*)(ws + 41287680);         // 6291456
  unsigned int* mp2 = (unsigned int*)(ws + 47579136);         // 6291456
  float* f2 = (float*)(ws + 41287680);                        // overlays mp1/mp2 (dead after attn)
  unsigned short* c1 = (unsigned short*)(ws + 53870592);      // 6291456
  unsigned short* c2 = (unsigned short*)(ws + 60162048);      // 6291456
  // total ~66.5 MB

  k_convert<<<3072, 256, 0, stream>>>(pro1, pro1b, 786432);
  k_convert<<<3072, 256, 0, stream>>>(pro2, pro2b, 786432);
  k_transpose<<<dim3(24, 24, 3), 256, 0, stream>>>(WQ, WK, FC1, wqt, wkt, fc1t);
  k_pack<<<dim3(64, BH), 256, 0, stream>>>(mask, mp1, mp2);
  k_gemm128<<<dim3(32, 6, 2), 256, 0, stream>>>(0, pro1b, pro2b, wqt, wkt, Qb, Kb, QT, KT, nullptr, nullptr);
  k_attn<<<dim3(16, BH, 2), 256, 0, stream>>>(Qb, Kb, QT, KT, mp1, mp2, c1, c2);
  k_gemm128<<<dim3(32, 6, 2), 256, 0, stream>>>(1, c1, c2, fc1t, fc1t, nullptr, nullptr, nullptr, nullptr, f1, f2);
  k_ln<<<8192, 256, 0, stream>>>(f1, f2, g1, b1, g2, b2, out);
}